// Round 5
// baseline (398.212 us; speedup 1.0000x reference)
//
#include <hip/hip_runtime.h>
#include <hip/hip_fp16.h>

#define NN 100000
#define NE 1600000
#define NG 256
#define NPB 32            // nodes per block-pass in layer kernel
#define LAYER_GRID 512

// binned CSR build
#define BSH 9                         // bucket = dst >> 9 (512 nodes/bucket)
#define NBKT ((NN + 511) / 512)       // 196
#define CAP 9216                      // per-bucket capacity (mean 8163, +11.7 sigma)
#define TILE_A 4096
#define NBLK_A ((NE + TILE_A - 1) / TILE_A)   // 391

__device__ __forceinline__ void acc4(float4& a, const float4& v) {
    a.x += v.x; a.y += v.y; a.z += v.z; a.w += v.w;
}

__device__ __forceinline__ float4 h16_to_f4(uint2 u) {
    __half2 a = *(__half2*)&u.x;
    __half2 b = *(__half2*)&u.y;
    float2 fa = __half22float2(a), fb = __half22float2(b);
    return make_float4(fa.x, fa.y, fb.x, fb.y);
}

__device__ __forceinline__ uint2 f4_to_h16(float4 o) {
    __half2 lo = __floats2half2_rn(o.x, o.y);
    __half2 hi = __floats2half2_rn(o.z, o.w);
    uint2 u;
    u.x = *(unsigned int*)&lo;
    u.y = *(unsigned int*)&hi;
    return u;
}

// ---------------- fp32 -> fp16 convert (for x) ----------------
__global__ __launch_bounds__(256) void cvt_kernel(const float* __restrict__ in,
                                                  __half* __restrict__ out) {
    const int i = blockIdx.x * 256 + threadIdx.x;   // one float4 per thread
    const int n4 = NN * 64 / 4;                     // 1.6M
    if (i < n4) {
        float4 v = ((const float4*)in)[i];
        ((uint2*)out)[i] = f4_to_h16(v);
    }
}

// ---------------- binned CSR build ----------------
__global__ __launch_bounds__(256) void initcur_kernel(int* __restrict__ gcur) {
    int t = threadIdx.x;
    if (t < NBKT) gcur[t] = t * CAP;
}

// Pass A: partition edges into NBKT buckets (packed u32 = src<<9 | (dst&511)),
// LDS-reordered so global writes are contiguous runs per (block,bucket).
__global__ __launch_bounds__(256) void binA_kernel(const int* __restrict__ src,
                                                   const int* __restrict__ dst,
                                                   int* __restrict__ gcur,
                                                   unsigned int* __restrict__ binned)
{
    __shared__ int hist[NBKT];
    __shared__ int cnt2[NBKT];
    __shared__ int lexcl[NBKT];
    __shared__ int base[NBKT];
    __shared__ int s[256];
    __shared__ unsigned int buf[TILE_A];
    __shared__ unsigned char bkt8[TILE_A];

    const int t = threadIdx.x;
    const int e0 = blockIdx.x * TILE_A;
    const int nedge = min(TILE_A, NE - e0);

    if (t < NBKT) { hist[t] = 0; cnt2[t] = 0; }
    __syncthreads();

    for (int j = t; j < nedge; j += 256)
        atomicAdd(&hist[dst[e0 + j] >> BSH], 1);
    __syncthreads();

    s[t] = (t < NBKT) ? hist[t] : 0;
    __syncthreads();
    for (int off = 1; off < 256; off <<= 1) {
        int u = (t >= off) ? s[t - off] : 0;
        __syncthreads();
        s[t] += u;
        __syncthreads();
    }
    if (t < NBKT) {
        lexcl[t] = s[t] - hist[t];
        if (hist[t] > 0) base[t] = atomicAdd(&gcur[t], hist[t]);
    }
    __syncthreads();

    for (int j = t; j < nedge; j += 256) {
        const int d = dst[e0 + j];
        const int sv = src[e0 + j];
        const int b = d >> BSH;
        const int r = atomicAdd(&cnt2[b], 1);
        const int idx = lexcl[b] + r;
        buf[idx] = ((unsigned int)sv << BSH) | (unsigned int)(d & 511);
        bkt8[idx] = (unsigned char)b;
    }
    __syncthreads();

    for (int j = t; j < nedge; j += 256) {
        const int b = bkt8[j];
        binned[base[b] + (j - lexcl[b])] = buf[j];
    }
}

__global__ __launch_bounds__(256) void bscan_kernel(const int* __restrict__ gcur,
                                                    int* __restrict__ bbase,
                                                    int* __restrict__ rs)
{
    __shared__ int s[256];
    const int t = threadIdx.x;
    const int sz = (t < NBKT) ? (gcur[t] - t * CAP) : 0;
    s[t] = sz;
    __syncthreads();
    for (int off = 1; off < 256; off <<= 1) {
        int u = (t >= off) ? s[t - off] : 0;
        __syncthreads();
        s[t] += u;
        __syncthreads();
    }
    if (t < NBKT) bbase[t] = s[t] - sz;
    if (t == 0) rs[NN] = NE;
}

__global__ __launch_bounds__(256) void binB_kernel(const unsigned int* __restrict__ binned,
                                                   const int* __restrict__ gcur,
                                                   const int* __restrict__ bbase,
                                                   int* __restrict__ csr,
                                                   int* __restrict__ rs)
{
    __shared__ int cnt[512];
    __shared__ int excl[512];
    __shared__ int cnt2[512];
    __shared__ int psum[256];
    __shared__ unsigned int buf[CAP];

    const int b = blockIdx.x;
    const int t = threadIdx.x;
    const int sz = gcur[b] - b * CAP;
    const int gb = bbase[b];
    const unsigned int* bp = binned + b * CAP;

    cnt[t] = 0; cnt[t + 256] = 0;
    cnt2[t] = 0; cnt2[t + 256] = 0;
    __syncthreads();

    for (int j = t; j < sz; j += 256) {
        const unsigned int v = bp[j];
        buf[j] = v;
        atomicAdd(&cnt[v & 511], 1);
    }
    __syncthreads();

    const int c0 = cnt[2 * t], c1 = cnt[2 * t + 1];
    psum[t] = c0 + c1;
    __syncthreads();
    for (int off = 1; off < 256; off <<= 1) {
        int u = (t >= off) ? psum[t - off] : 0;
        __syncthreads();
        psum[t] += u;
        __syncthreads();
    }
    const int pe = psum[t] - (c0 + c1);
    excl[2 * t] = pe;
    excl[2 * t + 1] = pe + c0;
    __syncthreads();

    const int node0 = b << BSH;
    for (int l = t; l < 512; l += 256) {
        const int node = node0 + l;
        if (node < NN) rs[node] = gb + excl[l];
    }

    for (int j = t; j < sz; j += 256) {
        const unsigned int v = buf[j];
        const int l = v & 511;
        const int r = atomicAdd(&cnt2[l], 1);
        csr[gb + excl[l] + r] = (int)(v >> BSH);
    }
}

// ---------------- fused GNN layer (fp16 h, fp32 accum/weights) ----------------
// out = relu( h@Wa+ba  +  agg(h)@Wc+bc  +  (h@Wb+bb)*(h@Wd+bd) )
__global__ __launch_bounds__(512, 4) void layer_kernel(
    const __half* __restrict__ h_in, __half* __restrict__ h_out,
    const int* __restrict__ csr, const int* __restrict__ rs,
    const float* __restrict__ Wa, const float* __restrict__ ba,
    const float* __restrict__ Wc, const float* __restrict__ bc,
    const float* __restrict__ Wb, const float* __restrict__ bb,
    const float* __restrict__ Wd, const float* __restrict__ bd)
{
    __shared__ float4 sWa[1024], sWc[1024], sWb[1024], sWd[1024];
    __shared__ __align__(16) float sh_h[NPB][64];
    __shared__ __align__(16) float sh_g[NPB][64];

    const int tid = threadIdx.x;
    for (int i = tid; i < 1024; i += 512) {
        sWa[i] = ((const float4*)Wa)[i];
        sWc[i] = ((const float4*)Wc)[i];
        sWb[i] = ((const float4*)Wb)[i];
        sWd[i] = ((const float4*)Wd)[i];
    }

    const int lane = tid & 63;
    const int wave = tid >> 6;
    const int nj   = lane >> 4;
    const int fg   = lane & 15;
    const int slot = wave * 4 + nj;

    const float4 bia  = ((const float4*)ba)[fg];
    const float4 bic  = ((const float4*)bc)[fg];
    const float4 bib  = ((const float4*)bb)[fg];
    const float4 bid_ = ((const float4*)bd)[fg];

    const int ngroups = (NN + NPB - 1) / NPB;
    for (int g = blockIdx.x; g < ngroups; g += gridDim.x) {
        const int node = g * NPB + slot;
        float4 h4 = make_float4(0.f, 0.f, 0.f, 0.f);
        float4 a4 = make_float4(0.f, 0.f, 0.f, 0.f);
        if (node < NN) {
            h4 = h16_to_f4(*(const uint2*)(h_in + node * 64 + fg * 4));
            int e = rs[node];
            const int ee = rs[node + 1];
            for (; e < ee; e += 8) {
                const int rem = ee - e;
                const int s0 = csr[e];
                const int s1 = rem > 1 ? csr[e + 1] : s0;
                const int s2 = rem > 2 ? csr[e + 2] : s0;
                const int s3 = rem > 3 ? csr[e + 3] : s0;
                const int s4 = rem > 4 ? csr[e + 4] : s0;
                const int s5 = rem > 5 ? csr[e + 5] : s0;
                const int s6 = rem > 6 ? csr[e + 6] : s0;
                const int s7 = rem > 7 ? csr[e + 7] : s0;
                const uint2 u0 = *(const uint2*)(h_in + s0 * 64 + fg * 4);
                const uint2 u1 = *(const uint2*)(h_in + s1 * 64 + fg * 4);
                const uint2 u2 = *(const uint2*)(h_in + s2 * 64 + fg * 4);
                const uint2 u3 = *(const uint2*)(h_in + s3 * 64 + fg * 4);
                const uint2 u4 = *(const uint2*)(h_in + s4 * 64 + fg * 4);
                const uint2 u5 = *(const uint2*)(h_in + s5 * 64 + fg * 4);
                const uint2 u6 = *(const uint2*)(h_in + s6 * 64 + fg * 4);
                const uint2 u7 = *(const uint2*)(h_in + s7 * 64 + fg * 4);
                acc4(a4, h16_to_f4(u0));
                if (rem > 1) acc4(a4, h16_to_f4(u1));
                if (rem > 2) acc4(a4, h16_to_f4(u2));
                if (rem > 3) acc4(a4, h16_to_f4(u3));
                if (rem > 4) acc4(a4, h16_to_f4(u4));
                if (rem > 5) acc4(a4, h16_to_f4(u5));
                if (rem > 6) acc4(a4, h16_to_f4(u6));
                if (rem > 7) acc4(a4, h16_to_f4(u7));
            }
        }
        __syncthreads();
        *(float4*)(&sh_h[slot][fg * 4]) = h4;
        *(float4*)(&sh_g[slot][fg * 4]) = a4;
        __syncthreads();

        float4 accA = {0.f,0.f,0.f,0.f}, accC = {0.f,0.f,0.f,0.f};
        float4 accB = {0.f,0.f,0.f,0.f}, accD = {0.f,0.f,0.f,0.f};
        #pragma unroll 8
        for (int k = 0; k < 64; ++k) {
            const float hk = sh_h[slot][k];
            const float gk = sh_g[slot][k];
            const float4 wa = sWa[k * 16 + fg];
            const float4 wc = sWc[k * 16 + fg];
            const float4 wb = sWb[k * 16 + fg];
            const float4 wd = sWd[k * 16 + fg];
            accA.x = fmaf(hk, wa.x, accA.x); accA.y = fmaf(hk, wa.y, accA.y);
            accA.z = fmaf(hk, wa.z, accA.z); accA.w = fmaf(hk, wa.w, accA.w);
            accC.x = fmaf(gk, wc.x, accC.x); accC.y = fmaf(gk, wc.y, accC.y);
            accC.z = fmaf(gk, wc.z, accC.z); accC.w = fmaf(gk, wc.w, accC.w);
            accB.x = fmaf(hk, wb.x, accB.x); accB.y = fmaf(hk, wb.y, accB.y);
            accB.z = fmaf(hk, wb.z, accB.z); accB.w = fmaf(hk, wb.w, accB.w);
            accD.x = fmaf(hk, wd.x, accD.x); accD.y = fmaf(hk, wd.y, accD.y);
            accD.z = fmaf(hk, wd.z, accD.z); accD.w = fmaf(hk, wd.w, accD.w);
        }
        if (node < NN) {
            float4 o;
            o.x = fmaxf((accA.x + bia.x) + (accC.x + bic.x) + (accB.x + bib.x) * (accD.x + bid_.x), 0.f);
            o.y = fmaxf((accA.y + bia.y) + (accC.y + bic.y) + (accB.y + bib.y) * (accD.y + bid_.y), 0.f);
            o.z = fmaxf((accA.z + bia.z) + (accC.z + bic.z) + (accB.z + bib.z) * (accD.z + bid_.z), 0.f);
            o.w = fmaxf((accA.w + bia.w) + (accC.w + bic.w) + (accB.w + bib.w) * (accD.w + bid_.w), 0.f);
            *(uint2*)(h_out + node * 64 + fg * 4) = f4_to_h16(o);
        }
    }
}

// ---------------- pool + MLP ----------------
__global__ __launch_bounds__(256) void pool_mlp_kernel(
    const __half* __restrict__ h, const int* __restrict__ batch,
    const float* __restrict__ w1, const float* __restrict__ b1,
    const float* __restrict__ w2, const float* __restrict__ b2,
    float* __restrict__ out)
{
    const int g = blockIdx.x;
    const int t = threadIdx.x;
    int lo = 0, hi = NN;
    while (lo < hi) { int m = (lo + hi) >> 1; if (batch[m] < g) lo = m + 1; else hi = m; }
    const int start = lo;
    hi = NN;
    while (lo < hi) { int m = (lo + hi) >> 1; if (batch[m] < g + 1) lo = m + 1; else hi = m; }
    const int end = lo;

    const int f = t & 63, wsub = t >> 6;
    float sum = 0.f;
    for (int n = start + wsub; n < end; n += 4) sum += __half2float(h[n * 64 + f]);
    __shared__ float red[4][64];
    red[wsub][f] = sum;
    __syncthreads();
    __shared__ float pooled[64];
    if (t < 64) {
        float tot = red[0][t] + red[1][t] + red[2][t] + red[3][t];
        pooled[t] = tot / fmaxf((float)(end - start), 1.f);
    }
    __syncthreads();
    __shared__ float y10[10];
    if (t < 10) {
        float acc = b1[t];
        for (int k = 0; k < 64; ++k) acc = fmaf(pooled[k], w1[k * 10 + t], acc);
        y10[t] = acc;
    }
    __syncthreads();
    if (t == 0) {
        float acc = b2[0];
        for (int j = 0; j < 10; ++j) acc = fmaf(y10[j], w2[j], acc);
        out[g] = acc;
    }
}

extern "C" void kernel_launch(void* const* d_in, const int* in_sizes, int n_in,
                              void* d_out, int out_size, void* d_ws, size_t ws_size,
                              hipStream_t stream) {
    const float* x    = (const float*)d_in[0];
    const int* ei     = (const int*)d_in[1];
    const int* batch  = (const int*)d_in[2];
    const int* src    = ei;
    const int* dstv   = ei + NE;

    // workspace layout (bytes), total ~40MB:
    //   hX16: [0, 12.8M)          (x16 for layer1; reused as hB16 output of layer2)
    //   hA16: [12.8M, 25.6M)      (layer1 out / layer2 in; layer3 out; pool in)
    //   csr:  [25.6M, 32.0M)
    //   rs:   [32.0M, +400004)
    //   binned: [32.5M, +7.23M)
    //   gcur/bbase: [39.8M, +2KB)
    char* ws     = (char*)d_ws;
    __half* hX16 = (__half*)(ws);
    __half* hA16 = (__half*)(ws + 12800000);
    int* csr     = (int*)(ws + 25600000);
    int* rs      = (int*)(ws + 32000000);
    unsigned int* binned = (unsigned int*)(ws + 32500000);
    int* gcur    = (int*)(ws + 39800000);
    int* bbase   = (int*)(ws + 39800000 + 1024);

    initcur_kernel<<<1, 256, 0, stream>>>(gcur);
    binA_kernel<<<NBLK_A, 256, 0, stream>>>(src, dstv, gcur, binned);
    bscan_kernel<<<1, 256, 0, stream>>>(gcur, bbase, rs);
    binB_kernel<<<NBKT, 256, 0, stream>>>(binned, gcur, bbase, csr, rs);
    cvt_kernel<<<(NN * 64 / 4 + 255) / 256, 256, 0, stream>>>(x, hX16);

    auto f = [&](int i) { return (const float*)d_in[i]; };
    layer_kernel<<<LAYER_GRID, 512, 0, stream>>>(hX16, hA16, csr, rs,
        f(5), f(6), f(3), f(4), f(7), f(8), f(9), f(10));
    layer_kernel<<<LAYER_GRID, 512, 0, stream>>>(hA16, hX16, csr, rs,
        f(13), f(14), f(11), f(12), f(15), f(16), f(17), f(18));
    layer_kernel<<<LAYER_GRID, 512, 0, stream>>>(hX16, hA16, csr, rs,
        f(21), f(22), f(19), f(20), f(23), f(24), f(25), f(26));

    pool_mlp_kernel<<<NG, 256, 0, stream>>>(hA16, batch,
        f(27), f(28), f(29), f(30), (float*)d_out);
}

// Round 6
// 217.176 us; speedup vs baseline: 1.8336x; 1.8336x over previous
//
#include <hip/hip_runtime.h>
#include <hip/hip_fp16.h>

#define NN 100000
#define NE 1600000
#define NG 256
#define NPB 64            // nodes per block-pass in layer kernel
#define LAYER_GRID 512

// binned CSR build
#define BSH 9                         // bucket = dst >> 9 (512 nodes/bucket)
#define NBKT ((NN + 511) / 512)       // 196
#define CAP 9216                      // per-bucket capacity (mean 8163, +11.7 sigma)
#define TILE_A 4096
#define NBLK_A ((NE + TILE_A - 1) / TILE_A)   // 391

typedef _Float16 f16x8 __attribute__((ext_vector_type(8)));
typedef float f32x4 __attribute__((ext_vector_type(4)));

__device__ __forceinline__ uint2 f4_to_h16(float4 o) {
    __half2 lo = __floats2half2_rn(o.x, o.y);
    __half2 hi = __floats2half2_rn(o.z, o.w);
    uint2 u;
    u.x = *(unsigned int*)&lo;
    u.y = *(unsigned int*)&hi;
    return u;
}

// ---------------- fp32 -> fp16 convert (for x) ----------------
__global__ __launch_bounds__(256) void cvt_kernel(const float* __restrict__ in,
                                                  __half* __restrict__ out) {
    const int i = blockIdx.x * 256 + threadIdx.x;   // one float4 per thread
    const int n4 = NN * 64 / 4;                     // 1.6M
    if (i < n4) {
        float4 v = ((const float4*)in)[i];
        ((uint2*)out)[i] = f4_to_h16(v);
    }
}

// ---------------- binned CSR build ----------------
__global__ __launch_bounds__(256) void initcur_kernel(int* __restrict__ gcur) {
    int t = threadIdx.x;
    if (t < NBKT) gcur[t] = t * CAP;
}

__global__ __launch_bounds__(256) void binA_kernel(const int* __restrict__ src,
                                                   const int* __restrict__ dst,
                                                   int* __restrict__ gcur,
                                                   unsigned int* __restrict__ binned)
{
    __shared__ int hist[NBKT];
    __shared__ int cnt2[NBKT];
    __shared__ int lexcl[NBKT];
    __shared__ int base[NBKT];
    __shared__ int s[256];
    __shared__ unsigned int buf[TILE_A];
    __shared__ unsigned char bkt8[TILE_A];

    const int t = threadIdx.x;
    const int e0 = blockIdx.x * TILE_A;
    const int nedge = min(TILE_A, NE - e0);

    if (t < NBKT) { hist[t] = 0; cnt2[t] = 0; }
    __syncthreads();

    for (int j = t; j < nedge; j += 256)
        atomicAdd(&hist[dst[e0 + j] >> BSH], 1);
    __syncthreads();

    s[t] = (t < NBKT) ? hist[t] : 0;
    __syncthreads();
    for (int off = 1; off < 256; off <<= 1) {
        int u = (t >= off) ? s[t - off] : 0;
        __syncthreads();
        s[t] += u;
        __syncthreads();
    }
    if (t < NBKT) {
        lexcl[t] = s[t] - hist[t];
        if (hist[t] > 0) base[t] = atomicAdd(&gcur[t], hist[t]);
    }
    __syncthreads();

    for (int j = t; j < nedge; j += 256) {
        const int d = dst[e0 + j];
        const int sv = src[e0 + j];
        const int b = d >> BSH;
        const int r = atomicAdd(&cnt2[b], 1);
        const int idx = lexcl[b] + r;
        buf[idx] = ((unsigned int)sv << BSH) | (unsigned int)(d & 511);
        bkt8[idx] = (unsigned char)b;
    }
    __syncthreads();

    for (int j = t; j < nedge; j += 256) {
        const int b = bkt8[j];
        binned[base[b] + (j - lexcl[b])] = buf[j];
    }
}

__global__ __launch_bounds__(256) void bscan_kernel(const int* __restrict__ gcur,
                                                    int* __restrict__ bbase,
                                                    int* __restrict__ rs)
{
    __shared__ int s[256];
    const int t = threadIdx.x;
    const int sz = (t < NBKT) ? (gcur[t] - t * CAP) : 0;
    s[t] = sz;
    __syncthreads();
    for (int off = 1; off < 256; off <<= 1) {
        int u = (t >= off) ? s[t - off] : 0;
        __syncthreads();
        s[t] += u;
        __syncthreads();
    }
    if (t < NBKT) bbase[t] = s[t] - sz;
    if (t == 0) rs[NN] = NE;
}

__global__ __launch_bounds__(256) void binB_kernel(const unsigned int* __restrict__ binned,
                                                   const int* __restrict__ gcur,
                                                   const int* __restrict__ bbase,
                                                   int* __restrict__ csr,
                                                   int* __restrict__ rs)
{
    __shared__ int cnt[512];
    __shared__ int excl[512];
    __shared__ int cnt2[512];
    __shared__ int psum[256];
    __shared__ unsigned int buf[CAP];

    const int b = blockIdx.x;
    const int t = threadIdx.x;
    const int sz = gcur[b] - b * CAP;
    const int gb = bbase[b];
    const unsigned int* bp = binned + b * CAP;

    cnt[t] = 0; cnt[t + 256] = 0;
    cnt2[t] = 0; cnt2[t + 256] = 0;
    __syncthreads();

    for (int j = t; j < sz; j += 256) {
        const unsigned int v = bp[j];
        buf[j] = v;
        atomicAdd(&cnt[v & 511], 1);
    }
    __syncthreads();

    const int c0 = cnt[2 * t], c1 = cnt[2 * t + 1];
    psum[t] = c0 + c1;
    __syncthreads();
    for (int off = 1; off < 256; off <<= 1) {
        int u = (t >= off) ? psum[t - off] : 0;
        __syncthreads();
        psum[t] += u;
        __syncthreads();
    }
    const int pe = psum[t] - (c0 + c1);
    excl[2 * t] = pe;
    excl[2 * t + 1] = pe + c0;
    __syncthreads();

    const int node0 = b << BSH;
    for (int l = t; l < 512; l += 256) {
        const int node = node0 + l;
        if (node < NN) rs[node] = gb + excl[l];
    }

    for (int j = t; j < sz; j += 256) {
        const unsigned int v = buf[j];
        const int l = v & 511;
        const int r = atomicAdd(&cnt2[l], 1);
        csr[gb + excl[l] + r] = (int)(v >> BSH);
    }
}

// ---------------- fused GNN layer: MFMA dense + gathered agg ----------------
// out = relu( h@Wa+ba  +  agg(h)@Wc+bc  +  (h@Wb+bb)*(h@Wd+bd) )
// 512 thr = 8 waves; pass = 64 nodes. Gather: 8 thr/node, uint4 rows, fp32 acc.
// Dense: mfma_f32_16x16x32_f16; A-frag row=l&15, k=(l>>4)*8+j (contiguous b128,
// m91-93-verified pattern); D: col=l&15, row=(l>>4)*4+reg (m89). Weights fp16
// transposed in LDS so B-frags are contiguous. Rows padded to 72 f16 (144B).
__device__ __forceinline__ void accu8(float* a8, uint4 u) {
    const __half2* hp = (const __half2*)&u;
    #pragma unroll
    for (int q = 0; q < 4; ++q) {
        float2 f = __half22float2(hp[q]);
        a8[2 * q] += f.x; a8[2 * q + 1] += f.y;
    }
}

__global__ __launch_bounds__(512, 4) void layer_kernel(
    const __half* __restrict__ h_in, __half* __restrict__ h_out,
    const int* __restrict__ csr, const int* __restrict__ rs,
    const float* __restrict__ Wa, const float* __restrict__ ba,
    const float* __restrict__ Wc, const float* __restrict__ bc,
    const float* __restrict__ Wb, const float* __restrict__ bb,
    const float* __restrict__ Wd, const float* __restrict__ bd)
{
    __shared__ _Float16 sX1[64][72];
    __shared__ _Float16 sX2[64][72];
    __shared__ _Float16 sW[4][64][72];   // [mat][n(col)][k], mats: 0=Wa 1=Wc 2=Wb 3=Wd

    const int tid = threadIdx.x;

    // one-time: weights fp32 -> fp16 transposed into LDS
    for (int e = tid; e < 4096; e += 512) {
        const int k = e >> 6, n = e & 63;
        sW[0][n][k] = (_Float16)Wa[e];
        sW[1][n][k] = (_Float16)Wc[e];
        sW[2][n][k] = (_Float16)Wb[e];
        sW[3][n][k] = (_Float16)Wd[e];
    }

    // gather-phase indexing: 8 threads per node
    const int slot = tid >> 3;      // 0..63
    const int fg8  = tid & 7;       // 16B feature chunk

    // mfma-phase indexing
    const int w   = tid >> 6;
    const int l   = tid & 63;
    const int lr  = l & 15;
    const int kh  = l >> 4;
    const int nt  = w & 3;
    const int mt0 = (w >> 2) * 16;      // region 1 row base (tiles 0/1)
    const int col = nt * 16 + lr;
    const float bA = ba[col], bC = bc[col], bB = bb[col], bD = bd[col];

    const int npass = (NN + NPB - 1) / NPB;
    for (int g = blockIdx.x; g < npass; g += gridDim.x) {
        const int node0 = g * NPB;

        // ---- gather phase (global reads only) ----
        const int node = node0 + slot;
        uint4 hreg = make_uint4(0u, 0u, 0u, 0u);
        float a8[8] = {0.f, 0.f, 0.f, 0.f, 0.f, 0.f, 0.f, 0.f};
        if (node < NN) {
            hreg = *(const uint4*)(h_in + node * 64 + fg8 * 8);
            int e = rs[node];
            const int ee = rs[node + 1];
            for (; e < ee; e += 8) {
                const int rem = ee - e;
                const int s0 = csr[e];
                const int s1 = rem > 1 ? csr[e + 1] : s0;
                const int s2 = rem > 2 ? csr[e + 2] : s0;
                const int s3 = rem > 3 ? csr[e + 3] : s0;
                const int s4 = rem > 4 ? csr[e + 4] : s0;
                const int s5 = rem > 5 ? csr[e + 5] : s0;
                const int s6 = rem > 6 ? csr[e + 6] : s0;
                const int s7 = rem > 7 ? csr[e + 7] : s0;
                const uint4 u0 = *(const uint4*)(h_in + s0 * 64 + fg8 * 8);
                const uint4 u1 = *(const uint4*)(h_in + s1 * 64 + fg8 * 8);
                const uint4 u2 = *(const uint4*)(h_in + s2 * 64 + fg8 * 8);
                const uint4 u3 = *(const uint4*)(h_in + s3 * 64 + fg8 * 8);
                const uint4 u4 = *(const uint4*)(h_in + s4 * 64 + fg8 * 8);
                const uint4 u5 = *(const uint4*)(h_in + s5 * 64 + fg8 * 8);
                const uint4 u6 = *(const uint4*)(h_in + s6 * 64 + fg8 * 8);
                const uint4 u7 = *(const uint4*)(h_in + s7 * 64 + fg8 * 8);
                accu8(a8, u0);
                if (rem > 1) accu8(a8, u1);
                if (rem > 2) accu8(a8, u2);
                if (rem > 3) accu8(a8, u3);
                if (rem > 4) accu8(a8, u4);
                if (rem > 5) accu8(a8, u5);
                if (rem > 6) accu8(a8, u6);
                if (rem > 7) accu8(a8, u7);
            }
        }
        __syncthreads();   // prev pass's LDS reads done (also covers weight staging)

        // ---- stage into LDS ----
        *(uint4*)&sX1[slot][fg8 * 8] = hreg;
        union { _Float16 h[8]; uint4 u; } cv;
        #pragma unroll
        for (int j = 0; j < 8; ++j) cv.h[j] = (_Float16)a8[j];
        *(uint4*)&sX2[slot][fg8 * 8] = cv.u;
        __syncthreads();

        // ---- MFMA phase: wave computes 2 regions (mt0, mt0+32) x Ntile nt ----
        f32x4 accA1 = {0.f,0.f,0.f,0.f}, accC1 = {0.f,0.f,0.f,0.f};
        f32x4 accB1 = {0.f,0.f,0.f,0.f}, accD1 = {0.f,0.f,0.f,0.f};
        f32x4 accA2 = {0.f,0.f,0.f,0.f}, accC2 = {0.f,0.f,0.f,0.f};
        f32x4 accB2 = {0.f,0.f,0.f,0.f}, accD2 = {0.f,0.f,0.f,0.f};
        #pragma unroll
        for (int kk = 0; kk < 2; ++kk) {
            const int ko = kk * 32 + kh * 8;
            const f16x8 wba = *(const f16x8*)&sW[0][col][ko];
            const f16x8 wbc = *(const f16x8*)&sW[1][col][ko];
            const f16x8 wbb = *(const f16x8*)&sW[2][col][ko];
            const f16x8 wbd = *(const f16x8*)&sW[3][col][ko];
            const f16x8 a1r0 = *(const f16x8*)&sX1[mt0 + lr][ko];
            const f16x8 a2r0 = *(const f16x8*)&sX2[mt0 + lr][ko];
            const f16x8 a1r1 = *(const f16x8*)&sX1[mt0 + 32 + lr][ko];
            const f16x8 a2r1 = *(const f16x8*)&sX2[mt0 + 32 + lr][ko];
            accA1 = __builtin_amdgcn_mfma_f32_16x16x32_f16(a1r0, wba, accA1, 0, 0, 0);
            accC1 = __builtin_amdgcn_mfma_f32_16x16x32_f16(a2r0, wbc, accC1, 0, 0, 0);
            accB1 = __builtin_amdgcn_mfma_f32_16x16x32_f16(a1r0, wbb, accB1, 0, 0, 0);
            accD1 = __builtin_amdgcn_mfma_f32_16x16x32_f16(a1r0, wbd, accD1, 0, 0, 0);
            accA2 = __builtin_amdgcn_mfma_f32_16x16x32_f16(a1r1, wba, accA2, 0, 0, 0);
            accC2 = __builtin_amdgcn_mfma_f32_16x16x32_f16(a2r1, wbc, accC2, 0, 0, 0);
            accB2 = __builtin_amdgcn_mfma_f32_16x16x32_f16(a1r1, wbb, accB2, 0, 0, 0);
            accD2 = __builtin_amdgcn_mfma_f32_16x16x32_f16(a1r1, wbd, accD2, 0, 0, 0);
        }

        // ---- epilogue: combine in regs, store fp16 ----
        #pragma unroll
        for (int r = 0; r < 4; ++r) {
            int row = mt0 + kh * 4 + r;
            int nd  = node0 + row;
            if (nd < NN) {
                float o = fmaxf((accA1[r] + bA) + (accC1[r] + bC) +
                                (accB1[r] + bB) * (accD1[r] + bD), 0.f);
                h_out[nd * 64 + col] = __float2half(o);
            }
            row += 32; nd += 32;
            if (nd < NN) {
                float o = fmaxf((accA2[r] + bA) + (accC2[r] + bC) +
                                (accB2[r] + bB) * (accD2[r] + bD), 0.f);
                h_out[nd * 64 + col] = __float2half(o);
            }
        }
    }
}

// ---------------- pool + MLP ----------------
__global__ __launch_bounds__(256) void pool_mlp_kernel(
    const __half* __restrict__ h, const int* __restrict__ batch,
    const float* __restrict__ w1, const float* __restrict__ b1,
    const float* __restrict__ w2, const float* __restrict__ b2,
    float* __restrict__ out)
{
    const int g = blockIdx.x;
    const int t = threadIdx.x;
    int lo = 0, hi = NN;
    while (lo < hi) { int m = (lo + hi) >> 1; if (batch[m] < g) lo = m + 1; else hi = m; }
    const int start = lo;
    hi = NN;
    while (lo < hi) { int m = (lo + hi) >> 1; if (batch[m] < g + 1) lo = m + 1; else hi = m; }
    const int end = lo;

    const int f = t & 63, wsub = t >> 6;
    float sum = 0.f;
    for (int n = start + wsub; n < end; n += 4) sum += __half2float(h[n * 64 + f]);
    __shared__ float red[4][64];
    red[wsub][f] = sum;
    __syncthreads();
    __shared__ float pooled[64];
    if (t < 64) {
        float tot = red[0][t] + red[1][t] + red[2][t] + red[3][t];
        pooled[t] = tot / fmaxf((float)(end - start), 1.f);
    }
    __syncthreads();
    __shared__ float y10[10];
    if (t < 10) {
        float acc = b1[t];
        for (int k = 0; k < 64; ++k) acc = fmaf(pooled[k], w1[k * 10 + t], acc);
        y10[t] = acc;
    }
    __syncthreads();
    if (t == 0) {
        float acc = b2[0];
        for (int j = 0; j < 10; ++j) acc = fmaf(y10[j], w2[j], acc);
        out[g] = acc;
    }
}

extern "C" void kernel_launch(void* const* d_in, const int* in_sizes, int n_in,
                              void* d_out, int out_size, void* d_ws, size_t ws_size,
                              hipStream_t stream) {
    const float* x    = (const float*)d_in[0];
    const int* ei     = (const int*)d_in[1];
    const int* batch  = (const int*)d_in[2];
    const int* src    = ei;
    const int* dstv   = ei + NE;

    // workspace layout (bytes), total ~40MB:
    //   hX16: [0, 12.8M)      hA16: [12.8M, 25.6M)
    //   csr:  [25.6M, 32.0M)  rs: [32.0M, +400004)
    //   binned: [32.5M, +7.23M)  gcur/bbase: [39.8M, +2KB)
    char* ws     = (char*)d_ws;
    __half* hX16 = (__half*)(ws);
    __half* hA16 = (__half*)(ws + 12800000);
    int* csr     = (int*)(ws + 25600000);
    int* rs      = (int*)(ws + 32000000);
    unsigned int* binned = (unsigned int*)(ws + 32500000);
    int* gcur    = (int*)(ws + 39800000);
    int* bbase   = (int*)(ws + 39800000 + 1024);

    initcur_kernel<<<1, 256, 0, stream>>>(gcur);
    binA_kernel<<<NBLK_A, 256, 0, stream>>>(src, dstv, gcur, binned);
    bscan_kernel<<<1, 256, 0, stream>>>(gcur, bbase, rs);
    binB_kernel<<<NBKT, 256, 0, stream>>>(binned, gcur, bbase, csr, rs);
    cvt_kernel<<<(NN * 64 / 4 + 255) / 256, 256, 0, stream>>>(x, hX16);

    auto f = [&](int i) { return (const float*)d_in[i]; };
    layer_kernel<<<LAYER_GRID, 512, 0, stream>>>(hX16, hA16, csr, rs,
        f(5), f(6), f(3), f(4), f(7), f(8), f(9), f(10));
    layer_kernel<<<LAYER_GRID, 512, 0, stream>>>(hA16, hX16, csr, rs,
        f(13), f(14), f(11), f(12), f(15), f(16), f(17), f(18));
    layer_kernel<<<LAYER_GRID, 512, 0, stream>>>(hX16, hA16, csr, rs,
        f(21), f(22), f(19), f(20), f(23), f(24), f(25), f(26));

    pool_mlp_kernel<<<NG, 256, 0, stream>>>(hA16, batch,
        f(27), f(28), f(29), f(30), (float*)d_out);
}